// Round 1
// baseline (1049.693 us; speedup 1.0000x reference)
//
#include <hip/hip_runtime.h>

static constexpr int ACT = 5;
static constexpr float PUNISH = -100.0f;
static constexpr float BIGNEG = 1.0e10f;
static constexpr int ITERS = 10;   // matches setup_inputs(); device scalar not host-readable under graph capture

#define BLK 256

// adj = logits - BIGNEG * illegal  (precomputed once)
__global__ void k_prep_adj(const float* __restrict__ logits,
                           const float* __restrict__ illegal,
                           float* __restrict__ adj, int na) {
    int i = blockIdx.x * BLK + threadIdx.x;
    if (i < na) adj[i] = fmaf(-BIGNEG, illegal[i], logits[i]);
}

// Compact live (mask != 0) pairs into (idx1, idx2, maskf). Order is
// nondeterministic (atomic counter) but only affects fp-atomic summation
// order downstream.
__global__ void k_pack(const int* __restrict__ pairs, int E,
                       int* __restrict__ i1, int* __restrict__ i2,
                       float* __restrict__ mv, int* __restrict__ cnt) {
    int t = blockIdx.x * BLK + threadIdx.x;
    if (t >= E) return;
    const int* r = pairs + 5 * t;
    int m = r[4];
    if (m == 0) return;
    int pos = atomicAdd(cnt, 1);
    i1[pos] = r[0] * ACT + r[1];
    i2[pos] = r[2] * ACT + r[3];
    mv[pos] = (float)m;
}

__device__ __forceinline__ void softmax5_store(const float q[ACT],
                                               float* __restrict__ probs, int base) {
    float mx = q[0];
#pragma unroll
    for (int a = 1; a < ACT; a++) mx = fmaxf(mx, q[a]);
    float e[ACT];
    float s = 0.f;
#pragma unroll
    for (int a = 0; a < ACT; a++) { e[a] = __expf(q[a] - mx); s += e[a]; }
    float inv = 1.0f / s;
#pragma unroll
    for (int a = 0; a < ACT; a++) probs[base + a] = e[a] * inv;
}

// iteration 1: q0 = -BIGNEG*illegal
__global__ void k_softmax_first(const float* __restrict__ illegal,
                                float* __restrict__ probs, int n) {
    int i = blockIdx.x * BLK + threadIdx.x;
    if (i >= n) return;
    int base = i * ACT;
    float q[ACT];
#pragma unroll
    for (int a = 0; a < ACT; a++) q[a] = -BIGNEG * illegal[base + a];
    softmax5_store(q, probs, base);
}

// iterations 2..T: q = adj + PUNISH * s
__global__ void k_softmax_step(const float* __restrict__ adj,
                               const float* __restrict__ s,
                               float* __restrict__ probs, int n) {
    int i = blockIdx.x * BLK + threadIdx.x;
    if (i >= n) return;
    int base = i * ACT;
    float q[ACT];
#pragma unroll
    for (int a = 0; a < ACT; a++) q[a] = fmaf(PUNISH, s[base + a], adj[base + a]);
    softmax5_store(q, probs, base);
}

// fallback variant when adj doesn't fit in ws
__global__ void k_softmax_step_noadj(const float* __restrict__ logits,
                                     const float* __restrict__ illegal,
                                     const float* __restrict__ s,
                                     float* __restrict__ probs, int n) {
    int i = blockIdx.x * BLK + threadIdx.x;
    if (i >= n) return;
    int base = i * ACT;
    float q[ACT];
#pragma unroll
    for (int a = 0; a < ACT; a++) {
        float adj = fmaf(-BIGNEG, illegal[base + a], logits[base + a]);
        q[a] = fmaf(PUNISH, s[base + a], adj);
    }
    softmax5_store(q, probs, base);
}

__global__ void k_scatter_packed(const int* __restrict__ i1, const int* __restrict__ i2,
                                 const float* __restrict__ mv, const int* __restrict__ cnt,
                                 const float* __restrict__ probs, float* __restrict__ s) {
    int t = blockIdx.x * BLK + threadIdx.x;
    int c = *cnt;
    if (t >= c) return;
    unsafeAtomicAdd(&s[i1[t]], probs[i2[t]] * mv[t]);
}

__global__ void k_scatter_raw(const int* __restrict__ pairs, int E,
                              const float* __restrict__ probs, float* __restrict__ s) {
    int t = blockIdx.x * BLK + threadIdx.x;
    if (t >= E) return;
    const int* r = pairs + 5 * t;
    int m = r[4];
    if (m == 0) return;
    unsafeAtomicAdd(&s[r[0] * ACT + r[1]], probs[r[2] * ACT + r[3]] * (float)m);
}

// out = adj + PUNISH*s  (vectorized)
__global__ void k_final(const float4* __restrict__ adj, const float4* __restrict__ s,
                        float4* __restrict__ out, int n4) {
    int i = blockIdx.x * BLK + threadIdx.x;
    if (i >= n4) return;
    float4 a = adj[i], p = s[i];
    float4 o;
    o.x = fmaf(PUNISH, p.x, a.x);
    o.y = fmaf(PUNISH, p.y, a.y);
    o.z = fmaf(PUNISH, p.z, a.z);
    o.w = fmaf(PUNISH, p.w, a.w);
    out[i] = o;
}

__global__ void k_final_noadj(const float* __restrict__ logits,
                              const float* __restrict__ illegal,
                              const float* __restrict__ s,
                              float* __restrict__ out, int na) {
    int i = blockIdx.x * BLK + threadIdx.x;
    if (i >= na) return;
    float adj = fmaf(-BIGNEG, illegal[i], logits[i]);
    out[i] = fmaf(PUNISH, s[i], adj);
}

extern "C" void kernel_launch(void* const* d_in, const int* in_sizes, int n_in,
                              void* d_out, int out_size, void* d_ws, size_t ws_size,
                              hipStream_t stream) {
    const float* logits  = (const float*)d_in[0];
    const float* illegal = (const float*)d_in[1];
    const int*   pairs   = (const int*)d_in[2];
    float* out = (float*)d_out;

    const int na = in_sizes[0];          // N*ACT = 2.5M
    const int n  = na / ACT;             // N
    const int E  = in_sizes[2] / 5;      // 2M

    auto cdiv = [](int a, int b) { return (a + b - 1) / b; };
    const size_t naB = (size_t)na * sizeof(float);
    const size_t packB = (size_t)E * 12 + 64;

    char* w = (char*)d_ws;

    float *adj = nullptr, *probs = nullptr, *s = nullptr;
    int *pi1 = nullptr, *pi2 = nullptr, *cnt = nullptr;
    float* pmv = nullptr;
    bool use_adj, use_pack;

    if (ws_size >= 3 * naB + packB) {            // full path (~54 MB)
        adj   = (float*)w;
        probs = (float*)(w + naB);
        s     = (float*)(w + 2 * naB);
        char* pw = w + 3 * naB;
        pi1 = (int*)pw;
        pi2 = (int*)(pw + (size_t)E * 4);
        pmv = (float*)(pw + (size_t)E * 8);
        cnt = (int*)(pw + (size_t)E * 12);
        use_adj = true; use_pack = true;
    } else if (ws_size >= 3 * naB) {             // no packing (~30 MB)
        adj   = (float*)w;
        probs = (float*)(w + naB);
        s     = (float*)(w + 2 * naB);
        use_adj = true; use_pack = false;
    } else if (ws_size >= 2 * naB) {             // probs lives in d_out (~20 MB)
        adj   = (float*)w;
        s     = (float*)(w + naB);
        probs = out;
        use_adj = true; use_pack = false;
    } else {                                     // minimal (~10 MB)
        s     = (float*)w;
        probs = out;
        use_adj = false; use_pack = false;
    }

    if (use_adj)
        k_prep_adj<<<cdiv(na, BLK), BLK, 0, stream>>>(logits, illegal, adj, na);
    if (use_pack) {
        hipMemsetAsync(cnt, 0, sizeof(int), stream);
        k_pack<<<cdiv(E, BLK), BLK, 0, stream>>>(pairs, E, pi1, pi2, pmv, cnt);
    }

    for (int t = 1; t <= ITERS; t++) {
        if (t == 1)
            k_softmax_first<<<cdiv(n, BLK), BLK, 0, stream>>>(illegal, probs, n);
        else if (use_adj)
            k_softmax_step<<<cdiv(n, BLK), BLK, 0, stream>>>(adj, s, probs, n);
        else
            k_softmax_step_noadj<<<cdiv(n, BLK), BLK, 0, stream>>>(logits, illegal, s, probs, n);

        hipMemsetAsync(s, 0, naB, stream);       // stream-ordered: softmax already consumed s

        if (use_pack)
            k_scatter_packed<<<cdiv(E, BLK), BLK, 0, stream>>>(pi1, pi2, pmv, cnt, probs, s);
        else
            k_scatter_raw<<<cdiv(E, BLK), BLK, 0, stream>>>(pairs, E, probs, s);
    }

    if (use_adj)
        k_final<<<cdiv(na / 4, BLK), BLK, 0, stream>>>((const float4*)adj, (const float4*)s,
                                                       (float4*)out, na / 4);
    else
        k_final_noadj<<<cdiv(na, BLK), BLK, 0, stream>>>(logits, illegal, s, out, na);
}

// Round 2
// 680.618 us; speedup vs baseline: 1.5423x; 1.5423x over previous
//
#include <hip/hip_runtime.h>

static constexpr int ACT = 5;
static constexpr float PUNISH = -100.0f;
static constexpr float BIGNEG = 1.0e10f;
static constexpr int ITERS = 10;   // matches setup_inputs(); device scalar unreadable under graph capture
#define BLK 256

// ---------------- softmax helper: 4 rows of 5, fully in registers ----------------
__device__ __forceinline__ void softmax4x5(const float* __restrict__ q, float* __restrict__ p) {
#pragma unroll
    for (int r = 0; r < 4; r++) {
        const float* v = q + 5 * r;
        float mx = v[0];
#pragma unroll
        for (int a = 1; a < 5; a++) mx = fmaxf(mx, v[a]);
        float e[5], ssum = 0.f;
#pragma unroll
        for (int a = 0; a < 5; a++) { e[a] = __expf(v[a] - mx); ssum += e[a]; }
        float inv = 1.0f / ssum;
#pragma unroll
        for (int a = 0; a < 5; a++) p[5 * r + a] = e[a] * inv;
    }
}

// ---------------- pack: wave-granular deterministic compaction (no atomics) ----------------
// Live pair p of wave w goes to slot w*64 + (#live lanes below it); wcnt[w] = #live in wave.
__global__ void k_pack(const int* __restrict__ pairs, int E,
                       int2* __restrict__ idx, float* __restrict__ mv,
                       unsigned char* __restrict__ wcnt) {
    int t = blockIdx.x * BLK + threadIdx.x;
    bool live = false;
    int i1 = 0, i2 = 0, m = 0;
    if (t < E) {
        const int* r = pairs + 5 * t;
        m = r[4];
        if (m != 0) {
            live = true;
            i1 = r[0] * ACT + r[1];
            i2 = r[2] * ACT + r[3];
        }
    }
    unsigned long long b = __ballot(live);
    int lane = threadIdx.x & 63;
    if (live) {
        int prefix = __popcll(b & ((1ull << lane) - 1));
        int pos = (t & ~63) + prefix;
        idx[pos] = make_int2(i1, i2);
        mv[pos] = (float)m;
    }
    if (lane == 0) wcnt[t >> 6] = (unsigned char)__popcll(b);
}

// ---------------- iteration 1: adj = logits - BIGNEG*illegal; probs = softmax(-BIGNEG*illegal); s = 0
__global__ void k_first(const float4* __restrict__ lg, const float4* __restrict__ il,
                        float4* __restrict__ adj, float4* __restrict__ probs,
                        float4* __restrict__ s, int nthread) {
    int i = blockIdx.x * BLK + threadIdx.x;
    if (i >= nthread) return;
    float q[20], p[20];
#pragma unroll
    for (int k = 0; k < 5; k++) {
        float4 a = lg[i * 5 + k];
        float4 b = il[i * 5 + k];
        float4 ad;
        ad.x = fmaf(-BIGNEG, b.x, a.x);
        ad.y = fmaf(-BIGNEG, b.y, a.y);
        ad.z = fmaf(-BIGNEG, b.z, a.z);
        ad.w = fmaf(-BIGNEG, b.w, a.w);
        adj[i * 5 + k] = ad;
        q[4 * k + 0] = -BIGNEG * b.x;
        q[4 * k + 1] = -BIGNEG * b.y;
        q[4 * k + 2] = -BIGNEG * b.z;
        q[4 * k + 3] = -BIGNEG * b.w;
    }
    softmax4x5(q, p);
    float4 z = make_float4(0.f, 0.f, 0.f, 0.f);
#pragma unroll
    for (int k = 0; k < 5; k++) {
        probs[i * 5 + k] = make_float4(p[4 * k], p[4 * k + 1], p[4 * k + 2], p[4 * k + 3]);
        s[i * 5 + k] = z;
    }
}

// ---------------- iterations 2..T: probs = softmax(adj + PUNISH*s); s = 0
__global__ void k_step(const float4* __restrict__ adj, float4* __restrict__ s,
                       float4* __restrict__ probs, int nthread) {
    int i = blockIdx.x * BLK + threadIdx.x;
    if (i >= nthread) return;
    float q[20], p[20];
#pragma unroll
    for (int k = 0; k < 5; k++) {
        float4 a = adj[i * 5 + k];
        float4 ss = s[i * 5 + k];
        q[4 * k + 0] = fmaf(PUNISH, ss.x, a.x);
        q[4 * k + 1] = fmaf(PUNISH, ss.y, a.y);
        q[4 * k + 2] = fmaf(PUNISH, ss.z, a.z);
        q[4 * k + 3] = fmaf(PUNISH, ss.w, a.w);
    }
    softmax4x5(q, p);
    float4 z = make_float4(0.f, 0.f, 0.f, 0.f);
#pragma unroll
    for (int k = 0; k < 5; k++) {
        probs[i * 5 + k] = make_float4(p[4 * k], p[4 * k + 1], p[4 * k + 2], p[4 * k + 3]);
        s[i * 5 + k] = z;
    }
}

// ---------------- scatter: s[i1] += probs[i2]*m over packed live pairs ----------------
__global__ void k_scatter(const int2* __restrict__ idx, const float* __restrict__ mv,
                          const unsigned char* __restrict__ wcnt,
                          const float* __restrict__ probs, float* __restrict__ s) {
    int t = blockIdx.x * BLK + threadIdx.x;
    int lane = t & 63;
    if (lane < (int)wcnt[t >> 6]) {
        int2 p = idx[t];
        unsafeAtomicAdd(&s[p.x], probs[p.y] * mv[t]);
    }
}

// ---------------- final: out = adj + PUNISH*s ----------------
__global__ void k_final(const float4* __restrict__ adj, const float4* __restrict__ s,
                        float4* __restrict__ out, int n4) {
    int i = blockIdx.x * BLK + threadIdx.x;
    if (i >= n4) return;
    float4 a = adj[i], ps = s[i];
    float4 o;
    o.x = fmaf(PUNISH, ps.x, a.x);
    o.y = fmaf(PUNISH, ps.y, a.y);
    o.z = fmaf(PUNISH, ps.z, a.z);
    o.w = fmaf(PUNISH, ps.w, a.w);
    out[i] = o;
}

// ---------------- scalar fallbacks (odd shapes / tiny workspace) ----------------
__global__ void k_softmax_first_sc(const float* __restrict__ illegal,
                                   float* __restrict__ probs, float* __restrict__ s, int n) {
    int i = blockIdx.x * BLK + threadIdx.x;
    if (i >= n) return;
    int base = i * ACT;
    float q[5], p[5];
#pragma unroll
    for (int a = 0; a < 5; a++) q[a] = -BIGNEG * illegal[base + a];
    float mx = q[0];
#pragma unroll
    for (int a = 1; a < 5; a++) mx = fmaxf(mx, q[a]);
    float ssum = 0.f;
#pragma unroll
    for (int a = 0; a < 5; a++) { p[a] = __expf(q[a] - mx); ssum += p[a]; }
    float inv = 1.0f / ssum;
#pragma unroll
    for (int a = 0; a < 5; a++) { probs[base + a] = p[a] * inv; s[base + a] = 0.f; }
}

__global__ void k_softmax_step_sc(const float* __restrict__ logits,
                                  const float* __restrict__ illegal,
                                  float* __restrict__ s,
                                  float* __restrict__ probs, int n) {
    int i = blockIdx.x * BLK + threadIdx.x;
    if (i >= n) return;
    int base = i * ACT;
    float q[5], p[5];
#pragma unroll
    for (int a = 0; a < 5; a++) {
        float adj = fmaf(-BIGNEG, illegal[base + a], logits[base + a]);
        q[a] = fmaf(PUNISH, s[base + a], adj);
    }
    float mx = q[0];
#pragma unroll
    for (int a = 1; a < 5; a++) mx = fmaxf(mx, q[a]);
    float ssum = 0.f;
#pragma unroll
    for (int a = 0; a < 5; a++) { p[a] = __expf(q[a] - mx); ssum += p[a]; }
    float inv = 1.0f / ssum;
#pragma unroll
    for (int a = 0; a < 5; a++) { probs[base + a] = p[a] * inv; s[base + a] = 0.f; }
}

__global__ void k_scatter_raw(const int* __restrict__ pairs, int E,
                              const float* __restrict__ probs, float* __restrict__ s) {
    int t = blockIdx.x * BLK + threadIdx.x;
    if (t >= E) return;
    const int* r = pairs + 5 * t;
    int m = r[4];
    if (m == 0) return;
    unsafeAtomicAdd(&s[r[0] * ACT + r[1]], probs[r[2] * ACT + r[3]] * (float)m);
}

__global__ void k_final_sc(const float* __restrict__ logits,
                           const float* __restrict__ illegal,
                           const float* __restrict__ s,
                           float* __restrict__ out, int na) {
    int i = blockIdx.x * BLK + threadIdx.x;
    if (i >= na) return;
    float adj = fmaf(-BIGNEG, illegal[i], logits[i]);
    out[i] = fmaf(PUNISH, s[i], adj);
}

extern "C" void kernel_launch(void* const* d_in, const int* in_sizes, int n_in,
                              void* d_out, int out_size, void* d_ws, size_t ws_size,
                              hipStream_t stream) {
    const float* logits  = (const float*)d_in[0];
    const float* illegal = (const float*)d_in[1];
    const int*   pairs   = (const int*)d_in[2];
    float* out = (float*)d_out;

    const int na = in_sizes[0];          // N*ACT
    const int n  = na / ACT;             // N
    const int E  = in_sizes[2] / 5;      // pair count
    const int nw = (E + 63) / 64;        // waves over pairs

    auto cdiv = [](int a, int b) { return (a + b - 1) / b; };
    const size_t naB = (size_t)na * sizeof(float);
    // layout: adj | s | idx(int2*E) | mv(float*E) | wcnt(nw)
    const size_t needB = 2 * naB + (size_t)E * 12 + (size_t)nw + 256;

    if (na % 20 == 0 && ws_size >= needB) {
        char* w = (char*)d_ws;
        float* adj = (float*)w;
        float* s   = (float*)(w + naB);
        int2*  idx = (int2*)(w + 2 * naB);
        float* mv  = (float*)(w + 2 * naB + (size_t)E * 8);
        unsigned char* wcnt = (unsigned char*)(w + 2 * naB + (size_t)E * 12);
        float* probs = out;              // d_out doubles as probs; overwritten by k_final

        const int nth = na / 20;         // 4 rows (20 floats, 5 float4) per thread

        k_pack<<<cdiv(E, BLK), BLK, 0, stream>>>(pairs, E, idx, mv, wcnt);

        for (int t = 1; t <= ITERS; t++) {
            if (t == 1)
                k_first<<<cdiv(nth, BLK), BLK, 0, stream>>>(
                    (const float4*)logits, (const float4*)illegal,
                    (float4*)adj, (float4*)probs, (float4*)s, nth);
            else
                k_step<<<cdiv(nth, BLK), BLK, 0, stream>>>(
                    (const float4*)adj, (float4*)s, (float4*)probs, nth);
            k_scatter<<<cdiv(E, BLK), BLK, 0, stream>>>(idx, mv, wcnt, probs, s);
        }
        k_final<<<cdiv(na / 4, BLK), BLK, 0, stream>>>(
            (const float4*)adj, (const float4*)s, (float4*)out, na / 4);
    } else {
        // generic fallback: s in ws, probs in d_out, re-derive adj on the fly
        float* s = (float*)d_ws;
        float* probs = out;
        for (int t = 1; t <= ITERS; t++) {
            if (t == 1)
                k_softmax_first_sc<<<cdiv(n, BLK), BLK, 0, stream>>>(illegal, probs, s, n);
            else
                k_softmax_step_sc<<<cdiv(n, BLK), BLK, 0, stream>>>(logits, illegal, s, probs, n);
            k_scatter_raw<<<cdiv(E, BLK), BLK, 0, stream>>>(pairs, E, probs, s);
        }
        k_final_sc<<<cdiv(na, BLK), BLK, 0, stream>>>(logits, illegal, s, out, na);
    }
}